// Round 11
// baseline (199.006 us; speedup 1.0000x reference)
//
#include <hip/hip_runtime.h>
#include <stdint.h>

typedef unsigned short u16;
typedef __attribute__((ext_vector_type(8))) short bf16x8;
typedef __attribute__((ext_vector_type(4))) short bf16x4;
typedef __attribute__((ext_vector_type(4))) float f32x4;
typedef __attribute__((ext_vector_type(4))) unsigned short u16x4;

// async global->LDS, 16B per lane, dest = wave-uniform base + lane*16
#define GLD16(gp, lp) __builtin_amdgcn_global_load_lds( \
    (__attribute__((address_space(1))) void*)(void*)(gp), \
    (__attribute__((address_space(3))) void*)(void*)(lp), 16, 0, 0)

__device__ __forceinline__ u16 f2b(float f) {  // fp32 -> bf16 bits, RNE
  union { float f; unsigned u; } v; v.f = f;
  unsigned r = v.u + 0x7FFFu + ((v.u >> 16) & 1u);
  return (u16)(r >> 16);
}

__device__ __forceinline__ float fexp2(float x) {
#if __has_builtin(__builtin_amdgcn_exp2f)
  return __builtin_amdgcn_exp2f(x);
#else
  return exp2f(x);
#endif
}

// ============================ LDS-image layouts ============================
// h_img[mt 0..63][kt 0..15][256r x 4chunks]: panel = 8192 u16 (16 KB).
//   slot(r, c8, j) = r*32 + ((c8 ^ ((r>>1)&3))*8) + j    (c8 = 8-ch chunk)
// w_img[nt 0..15][kt 0..15][96r x 4chunks]: panel = 3072 u16 (6 KB), same
//   per-row swizzle. Staging a panel = flat GLD16 copy (1 KB/wave-instr).
// ===========================================================================

// ---------------- fused: GroupNorm (blocks 0..511) + weight cvt (512..1535)
__global__ __launch_bounds__(256) void gncvt_kernel(const float* __restrict__ x,
                                                    const float* __restrict__ gw,
                                                    const float* __restrict__ gb,
                                                    u16* __restrict__ h,
                                                    const float* __restrict__ wq_f,
                                                    const float* __restrict__ wo_f,
                                                    u16* __restrict__ wq,
                                                    u16* __restrict__ wo) {
  if (blockIdx.x >= 512) {
    int i = (blockIdx.x - 512) * 256 + threadIdx.x;   // 0 .. 262143
    if (i < 196608) {
      // proj_w -> w_img: row n = i>>7, channels c0 = (i&127)*4
      const float4 f = ((const float4*)wq_f)[i];
      const int n = i >> 7, c0 = (i & 127) * 4;
      const int nt = n / 96, r = n - nt * 96;
      const int kt = c0 >> 5, c8 = (c0 >> 3) & 3, wi = c0 & 7;
      const int sel = (r >> 1) & 3;
      u16x4 rr; rr[0] = f2b(f.x); rr[1] = f2b(f.y); rr[2] = f2b(f.z); rr[3] = f2b(f.w);
      *(u16x4*)(wq + (size_t)(nt * 16 + kt) * 3072 + r * 32 + ((c8 ^ sel) * 8) + wi) = rr;
    } else {
      int j = i - 196608;
      const float4 f = ((const float4*)wo_f)[j];
      u16x4 rr; rr[0] = f2b(f.x); rr[1] = f2b(f.y); rr[2] = f2b(f.z); rr[3] = f2b(f.w);
      *(u16x4*)(wo + (size_t)j * 4) = rr;
    }
    return;
  }
  const int b = blockIdx.x >> 5, g = blockIdx.x & 31;
  const float* xg = x + ((size_t)(b * 512 + g * 16)) * 1024;
  const int tid = threadIdx.x;
  float4 vals[16];                 // vals[j] = channel j, pixels 4t..4t+3
  float s = 0.f, ss = 0.f;
#pragma unroll
  for (int j = 0; j < 16; j++) {
    const float4 v = ((const float4*)xg)[j * 256 + tid];
    vals[j] = v;
    s  += (v.x + v.y) + (v.z + v.w);
    ss += (v.x * v.x + v.y * v.y) + (v.z * v.z + v.w * v.w);
  }
#pragma unroll
  for (int off = 32; off; off >>= 1) { s += __shfl_down(s, off); ss += __shfl_down(ss, off); }
  __shared__ float red[8];
  const int wid = tid >> 6, lane = tid & 63;
  if (lane == 0) { red[wid] = s; red[4 + wid] = ss; }
  __syncthreads();
  if (tid == 0) {
    float S = red[0] + red[1] + red[2] + red[3];
    float SS = red[4] + red[5] + red[6] + red[7];
    float mean = S * (1.f / 16384.f);
    float var = SS * (1.f / 16384.f) - mean * mean;
    red[0] = mean; red[1] = rsqrtf(var + 1e-5f);
  }
  __syncthreads();
  const float mean = red[0], rs = red[1];
  float sc[16], bi[16];
#pragma unroll
  for (int c = 0; c < 16; c++) { sc[c] = gw[g * 16 + c] * rs; bi[c] = gb[g * 16 + c]; }
  // write into h_img: this block owns chunks {2(g&1), 2(g&1)+1} of kt = g>>1
  const int mt = b * 4 + (tid >> 6);
  const int kt = g >> 1, c8a = (g & 1) * 2;
  u16* base = h + (size_t)(mt * 16 + kt) * 8192;
#pragma unroll
  for (int e = 0; e < 4; e++) {
    const int r = (tid & 63) * 4 + e;
    const int sel = (r >> 1) & 3;
    u16 row[16];
#pragma unroll
    for (int j = 0; j < 16; j++) {
      const float v = (e == 0) ? vals[j].x : (e == 1) ? vals[j].y : (e == 2) ? vals[j].z : vals[j].w;
      row[j] = f2b((v - mean) * sc[j] + bi[j]);
    }
    *(bf16x8*)(base + r * 32 + ((c8a ^ sel) * 8)) = *(bf16x8*)&row[0];
    *(bf16x8*)(base + r * 32 + (((c8a + 1) ^ sel) * 8)) = *(bf16x8*)&row[8];
  }
}

// ---------------- QKV GEMM v7: 2-deep pipeline (counted vmcnt) ------------
__global__ __launch_bounds__(512, 4) void qkv_gemm(const u16* __restrict__ h,
                                                   const u16* __restrict__ w,
                                                   const float* __restrict__ bias,
                                                   u16* __restrict__ q,
                                                   u16* __restrict__ k,
                                                   u16* __restrict__ v) {
  __shared__ u16 Hs[3][8192];   // 3 x 16 KB
  __shared__ u16 Ws[3][3072];   // 3 x 6 KB
  const int bm = blockIdx.x;    // 0..63  (256 s)
  const int bn = blockIdx.y;    // 0..15  (96 channels)
  const int tid = threadIdx.x, lane = tid & 63, wid = tid >> 6;
  const int wm = wid >> 1, wn = wid & 1;     // wm: 4 s-col waves, wn: 2 ch-row waves
  const int c15 = lane & 15, quad = lane >> 4;
  const int kc = ((quad ^ ((c15 >> 1) & 3)) * 8);   // phys chunk offset (u16)

  const u16* pA = h + (size_t)bm * 16 * 8192 + (size_t)tid * 8;   // + kt*8192
  const u16* pB = w + (size_t)bn * 16 * 3072 + (size_t)tid * 8;   // + kt*3072
  const bool doB = (tid < 384);

  const f32x4 fz = {0.f, 0.f, 0.f, 0.f};
  f32x4 acc[3][4];              // [ch-tile ci][s-tile si]
#pragma unroll
  for (int i = 0; i < 3; i++)
#pragma unroll
    for (int j = 0; j < 4; j++) acc[i][j] = fz;

#define STAGE(T, B) { const u16* a_ = pA + (size_t)(T) * 8192; \
    GLD16(a_, &Hs[B][tid * 8]); \
    GLD16(a_ + 4096, &Hs[B][4096 + tid * 8]); \
    if (doB) GLD16(pB + (size_t)(T) * 3072, &Ws[B][tid * 8]); }

  // prologue: tiles 0,1 in flight
  STAGE(0, 0)
  STAGE(1, 1)

#pragma unroll
  for (int kt = 0; kt < 16; ++kt) {
    const int cb = kt % 3;
    __builtin_amdgcn_s_barrier();      // readers of buf (kt+2)%3 (tile kt-1) done
    if (kt < 14) STAGE(kt + 2, (kt + 2) % 3)
    // counted wait: tile kt's loads are the oldest; leave tiles kt+1,kt+2 in flight
    if (kt < 14) {
      if (doB) asm volatile("s_waitcnt vmcnt(6)" ::: "memory");
      else     asm volatile("s_waitcnt vmcnt(4)" ::: "memory");
    } else if (kt == 14) {
      if (doB) asm volatile("s_waitcnt vmcnt(3)" ::: "memory");
      else     asm volatile("s_waitcnt vmcnt(2)" ::: "memory");
    } else {
      asm volatile("s_waitcnt vmcnt(0)" ::: "memory");
    }
    __builtin_amdgcn_s_barrier();      // publish tile kt (all waves' loads done)
    __builtin_amdgcn_sched_barrier(0);
    bf16x8 af[3], bf[4];
#pragma unroll
    for (int ci = 0; ci < 3; ci++)
      af[ci] = *(const bf16x8*)&Ws[cb][(wn * 48 + ci * 16 + c15) * 32 + kc];
#pragma unroll
    for (int si = 0; si < 4; si++)
      bf[si] = *(const bf16x8*)&Hs[cb][(wm * 64 + si * 16 + c15) * 32 + kc];
    __builtin_amdgcn_s_setprio(1);
#pragma unroll
    for (int ci = 0; ci < 3; ci++)
#pragma unroll
      for (int si = 0; si < 4; si++)
        acc[ci][si] = __builtin_amdgcn_mfma_f32_16x16x32_bf16(af[ci], bf[si], acc[ci][si], 0, 0, 0);
    __builtin_amdgcn_s_setprio(0);
  }
#undef STAGE

  const float qscale = 0.51006972f;            // 2^-1.5 * log2(e)
  const float kscale = 0.35355339059327373f;   // 2^-1.5
  const int b = bm >> 2;
#pragma unroll
  for (int ci = 0; ci < 3; ci++) {
    const int n0 = bn * 96 + wn * 48 + ci * 16 + quad * 4;   // rows n0..n0+3
    const int head = n0 / 192;
    const int rr = n0 - head * 192;
    const int d0 = rr & 63;
    const float4 bi4 = *(const float4*)&bias[n0];
    const float bb[4] = {bi4.x, bi4.y, bi4.z, bi4.w};
#pragma unroll
    for (int si = 0; si < 4; si++) {
      const int sp = (bm & 3) * 256 + wm * 64 + si * 16 + c15;
      if (rr < 128) {
        u16* dst = ((rr < 64) ? q : k) + ((size_t)(b * 8 + head) * 1024 + sp) * 64 + d0;
        const float sc = (rr < 64) ? qscale : kscale;
        u16x4 pk;
#pragma unroll
        for (int r = 0; r < 4; r++) pk[r] = f2b((acc[ci][si][r] + bb[r]) * sc);
        *(u16x4*)dst = pk;
      } else {
#pragma unroll
        for (int r = 0; r < 4; r++)
          v[((size_t)(b * 8 + head) * 64 + d0 + r) * 1024 + sp] = f2b(acc[ci][si][r] + bb[r]);
      }
    }
  }
}

// ---------------- flash attention v12: KVBLK=128 (2 halves per barrier) ----
// v11 softmax/PV body unchanged; K/V buffers doubled to 128 keys, processed
// as two independent 64-key halves inside ONE barrier window. Barriers drop
// 16 -> 8 and half0's exp2/perm VALU burst co-issues with half1's QK MFMAs
// (they are data-independent until the oaccT accumulate). LDS 64 KB, still
// 2 blocks/CU (grid 512 = exactly 2/CU resident).
__global__ __launch_bounds__(512) void attn_kernel(const u16* __restrict__ q,
                                                   const u16* __restrict__ k,
                                                   const u16* __restrict__ vT,
                                                   u16* __restrict__ o) {
  __shared__ u16 Ks[2][2][64 * 64];   // [buf][half]
  __shared__ u16 Vs[2][2][64 * 64];
  const int bh = blockIdx.x;
  const int qb = blockIdx.y;      // 0..3
  const int tid = threadIdx.x, lane = tid & 63, wid = tid >> 6;   // wid 0..7
  const u16* Q = q + (size_t)bh * 1024 * 64;
  const u16* K = k + (size_t)bh * 1024 * 64;
  const u16* V = vT + (size_t)bh * 64 * 1024;
  const int qrow0 = qb * 256 + wid * 32;
  const int c15 = lane & 15, quad = lane >> 4;
  const int sw = c15 & 7;                  // read-side swizzle component
  const int srow = tid >> 3;               // 0..63
  const int u8g  = tid & 7;                // 8-col group (K) / 8-key group (V)
  const int s7 = srow & 7;
  const int kld = srow * 64 + ((u8g ^ s7) * 8);
  const int ve = 4 * (u8g >> 2) + 2 * (u8g & 1);   // pc0>>1
  const int vc = ((u8g >> 1) & 1) * 4;             // (pc0&1)*4
  const int vld0 = srow * 64 + ((ve ^ s7) * 8) + vc;
  const int vld1 = srow * 64 + (((ve + 1) ^ s7) * 8) + vc;

  bf16x8 qf[2][2];
#pragma unroll
  for (int kk = 0; kk < 2; kk++)
#pragma unroll
    for (int ni = 0; ni < 2; ni++)
      qf[kk][ni] = *(const bf16x8*)(Q + (size_t)(qrow0 + ni * 16 + c15) * 64 + kk * 32 + quad * 8);

  const f32x4 fz = {0.f, 0.f, 0.f, 0.f};
  const float Mshift = 14.4269504089f;     // 10 * log2(e)
  const f32x4 fmseed = {-Mshift, -Mshift, -Mshift, -Mshift};
  bf16x8 vone;
#pragma unroll
  for (int i = 0; i < 8; i++) vone[i] = (short)0x3F80;   // bf16 1.0
  f32x4 oaccT[4][2];               // O^T[d-tile nd][qrow-tile ni]
#pragma unroll
  for (int i = 0; i < 4; i++)
#pragma unroll
    for (int j = 0; j < 2; j++) oaccT[i][j] = fz;
  f32x4 accl[2] = {fz, fz};        // denominator via ones-MFMA

  bf16x8 kr[2], vr[2];
#pragma unroll
  for (int h2 = 0; h2 < 2; h2++) {
    kr[h2] = *(const bf16x8*)(K + (size_t)(h2 * 64 + srow) * 64 + u8g * 8);
    vr[h2] = *(const bf16x8*)(V + (size_t)srow * 1024 + h2 * 64 + u8g * 8);
  }
  {
#pragma unroll
    for (int h2 = 0; h2 < 2; h2++) {
      *(bf16x8*)&Ks[0][h2][kld] = kr[h2];
      union { bf16x4 h[2]; bf16x8 v; } a; a.v = vr[h2];
      *(bf16x4*)&Vs[0][h2][vld0] = a.h[0];
      *(bf16x4*)&Vs[0][h2][vld1] = a.h[1];
    }
  }
#pragma unroll
  for (int h2 = 0; h2 < 2; h2++) {
    kr[h2] = *(const bf16x8*)(K + (size_t)(128 + h2 * 64 + srow) * 64 + u8g * 8);
    vr[h2] = *(const bf16x8*)(V + (size_t)srow * 1024 + 128 + h2 * 64 + u8g * 8);
  }

  for (int kt2 = 0; kt2 < 8; ++kt2) {
    __syncthreads();   // publish buf[kt2&1]; retire readers of the other buf
    const int cur = kt2 & 1, alt = cur ^ 1;
    if (kt2 < 7) {
#pragma unroll
      for (int h2 = 0; h2 < 2; h2++) {
        *(bf16x8*)&Ks[alt][h2][kld] = kr[h2];
        union { bf16x4 h[2]; bf16x8 v; } a; a.v = vr[h2];
        *(bf16x4*)&Vs[alt][h2][vld0] = a.h[0];
        *(bf16x4*)&Vs[alt][h2][vld1] = a.h[1];
      }
      const int pk2 = (kt2 + 2) & 7;   // wraps harmlessly at the tail
#pragma unroll
      for (int h2 = 0; h2 < 2; h2++) {
        kr[h2] = *(const bf16x8*)(K + (size_t)(pk2 * 128 + h2 * 64 + srow) * 64 + u8g * 8);
        vr[h2] = *(const bf16x8*)(V + (size_t)srow * 1024 + pk2 * 128 + h2 * 64 + u8g * 8);
      }
    }

#pragma unroll
    for (int hf = 0; hf < 2; hf++) {
      const u16* Kc = Ks[cur][hf];
      const u16* Vc = Vs[cur][hf];

      // S^T = K Q^T; kk=0 seeds D with fmseed via the C operand
      f32x4 sacc[4][2];
      {
        bf16x8 af[4];
#pragma unroll
        for (int mi = 0; mi < 4; mi++)
          af[mi] = *(const bf16x8*)&Kc[(mi * 16 + c15) * 64 + (((quad) ^ sw) * 8)];
        __builtin_amdgcn_s_setprio(1);
#pragma unroll
        for (int mi = 0; mi < 4; mi++)
#pragma unroll
          for (int ni = 0; ni < 2; ni++)
            sacc[mi][ni] = __builtin_amdgcn_mfma_f32_16x16x32_bf16(af[mi], qf[0][ni], fmseed, 0, 0, 0);
        __builtin_amdgcn_s_setprio(0);
      }
      {
        bf16x8 af[4];
#pragma unroll
        for (int mi = 0; mi < 4; mi++)
          af[mi] = *(const bf16x8*)&Kc[(mi * 16 + c15) * 64 + (((4 + quad) ^ sw) * 8)];
        __builtin_amdgcn_s_setprio(1);
#pragma unroll
        for (int mi = 0; mi < 4; mi++)
#pragma unroll
          for (int ni = 0; ni < 2; ni++)
            sacc[mi][ni] = __builtin_amdgcn_mfma_f32_16x16x32_bf16(af[mi], qf[1][ni], sacc[mi][ni], 0, 0, 0);
        __builtin_amdgcn_s_setprio(0);
      }

      // P = exp2(s') packed to bf16 pairs IN REGISTERS
      unsigned pkd[4][2][2];   // [key-tile mi][ni][dword]
#pragma unroll
      for (int ni = 0; ni < 2; ni++) {
#pragma unroll
        for (int mi = 0; mi < 4; mi++) {
          unsigned pu[4];
#pragma unroll
          for (int r = 0; r < 4; r++) {
            const float p = fexp2(sacc[mi][ni][r]);
            union { float f; unsigned u; } c; c.f = p;
            pu[r] = c.u;
          }
          pkd[mi][ni][0] = __builtin_amdgcn_perm(pu[1], pu[0], 0x07060302u);
          pkd[mi][ni][1] = __builtin_amdgcn_perm(pu[3], pu[2], 0x07060302u);
        }
      }

      // O^T += V^T P^T ; l += ones^T P^T
#pragma unroll
      for (int mg = 0; mg < 2; mg++) {
        union { unsigned u[4]; bf16x8 v; } bb[2];
#pragma unroll
        for (int ni = 0; ni < 2; ni++) {
          bb[ni].u[0] = pkd[2 * mg][ni][0];     bb[ni].u[1] = pkd[2 * mg][ni][1];
          bb[ni].u[2] = pkd[2 * mg + 1][ni][0]; bb[ni].u[3] = pkd[2 * mg + 1][ni][1];
        }
        bf16x8 aa[4];
#pragma unroll
        for (int nd = 0; nd < 4; nd++)
          aa[nd] = *(const bf16x8*)&Vc[(nd * 16 + c15) * 64 + (((mg * 4 + quad) ^ sw) * 8)];
        __builtin_amdgcn_s_setprio(1);
#pragma unroll
        for (int nd = 0; nd < 4; nd++)
#pragma unroll
          for (int ni = 0; ni < 2; ni++)
            oaccT[nd][ni] = __builtin_amdgcn_mfma_f32_16x16x32_bf16(aa[nd], bb[ni].v, oaccT[nd][ni], 0, 0, 0);
#pragma unroll
        for (int ni = 0; ni < 2; ni++)
          accl[ni] = __builtin_amdgcn_mfma_f32_16x16x32_bf16(vone, bb[ni].v, accl[ni], 0, 0, 0);
        __builtin_amdgcn_s_setprio(0);
      }
    }
  }

  // denominator already per-qrow in accl (all rows/regs equal) — no shfl
  float iv[2];
#pragma unroll
  for (int ni = 0; ni < 2; ni++) iv[ni] = 1.f / accl[ni][0];
  const int b = bh >> 3, hh = bh & 7;
#pragma unroll
  for (int ni = 0; ni < 2; ni++) {
    const int row = qrow0 + ni * 16 + c15;
#pragma unroll
    for (int nd = 0; nd < 4; nd++) {
      u16x4 pk4;
#pragma unroll
      for (int r = 0; r < 4; r++) pk4[r] = f2b(oaccT[nd][ni][r] * iv[ni]);
      *(u16x4*)(o + ((size_t)b * 1024 + row) * 512 + hh * 64 + nd * 16 + quad * 4) = pk4;
    }
  }
}

// ---------------- out proj v2: 2-deep counted-vmcnt pipeline --------------
__global__ __launch_bounds__(256) void out_gemm(const u16* __restrict__ attn,
                                                const u16* __restrict__ wo,
                                                const float* __restrict__ ob,
                                                const float* __restrict__ x,
                                                float* __restrict__ out) {
  __shared__ u16 As[3][4096];   // 3 x 8 KB
  __shared__ u16 Bs[3][4096];   // 3 x 8 KB
  const int b = blockIdx.z;
  const int bm = blockIdx.x;      // s-tile 0..7
  const int bn = blockIdx.y;      // c-tile 0..3
  const int tid = threadIdx.x, lane = tid & 63, wid = tid >> 6;
  const int wm = wid & 1, wn = wid >> 1;
  const u16* gA = attn + ((size_t)b * 1024 + bm * 128) * 512;
  const u16* gB = wo + (size_t)bn * 128 * 512;

  const f32x4 fz = {0.f, 0.f, 0.f, 0.f};
  f32x4 acc[4][4];
#pragma unroll
  for (int i = 0; i < 4; i++)
#pragma unroll
    for (int j = 0; j < 4; j++) acc[i][j] = fz;

  const int r0 = lane >> 2;
  const int ch8 = (lane & 3) * 8;

#define OSTAGE(T, B) { \
    _Pragma("unroll") \
    for (int j_ = 0; j_ < 2; ++j_) { \
      const int idx_ = wid * 2 + j_; \
      const int row_ = idx_ * 16 + r0; \
      GLD16(gA + (size_t)row_ * 512 + (T) * 32 + ch8, &As[B][idx_ * 512 + lane * 8]); \
      GLD16(gB + (size_t)row_ * 512 + (T) * 32 + ch8, &Bs[B][idx_ * 512 + lane * 8]); \
    } }

  // prologue: tiles 0,1 in flight (8 loads/thread)
  OSTAGE(0, 0)
  OSTAGE(1, 1)

#pragma unroll
  for (int kt = 0; kt < 16; ++kt) {
    const int cb = kt % 3;
    __builtin_amdgcn_s_barrier();      // readers of buf (kt+2)%3 (tile kt-1) done
    if (kt < 14) OSTAGE(kt + 2, (kt + 2) % 3)
    // counted wait: tile kt's 4 loads are the oldest outstanding
    if (kt < 14)       asm volatile("s_waitcnt vmcnt(8)" ::: "memory");
    else if (kt == 14) asm volatile("s_waitcnt vmcnt(4)" ::: "memory");
    else               asm volatile("s_waitcnt vmcnt(0)" ::: "memory");
    __builtin_amdgcn_s_barrier();      // publish tile kt
    __builtin_amdgcn_sched_barrier(0);
    bf16x8 af[4], bf[4];
#pragma unroll
    for (int mi = 0; mi < 4; mi++)
      af[mi] = *(const bf16x8*)&As[cb][(wm * 64 + mi * 16 + (lane & 15)) * 32 + (lane >> 4) * 8];
#pragma unroll
    for (int ni = 0; ni < 4; ni++)
      bf[ni] = *(const bf16x8*)&Bs[cb][(wn * 64 + ni * 16 + (lane & 15)) * 32 + (lane >> 4) * 8];
    __builtin_amdgcn_s_setprio(1);
#pragma unroll
    for (int mi = 0; mi < 4; mi++)
#pragma unroll
      for (int ni = 0; ni < 4; ni++)
        acc[mi][ni] = __builtin_amdgcn_mfma_f32_16x16x32_bf16(af[mi], bf[ni], acc[mi][ni], 0, 0, 0);
    __builtin_amdgcn_s_setprio(0);
  }
#undef OSTAGE

  const int quad4 = (lane >> 4) << 2;
  const int c15_ = lane & 15;
#pragma unroll
  for (int mi = 0; mi < 4; mi++) {
    const int m = bm * 128 + wm * 64 + mi * 16 + quad4;   // s base (rows m..m+3)
#pragma unroll
    for (int ni = 0; ni < 4; ni++) {
      const int c = bn * 128 + wn * 64 + ni * 16 + c15_;
      const float bo = ob[c];
      const size_t idx = ((size_t)b * 512 + c) * 1024 + m;
      const float4 xv = *(const float4*)(x + idx);
      float4 ov;
      ov.x = acc[mi][ni][0] + bo + xv.x;
      ov.y = acc[mi][ni][1] + bo + xv.y;
      ov.z = acc[mi][ni][2] + bo + xv.z;
      ov.w = acc[mi][ni][3] + bo + xv.w;
      *(float4*)(out + idx) = ov;
    }
  }
}

extern "C" void kernel_launch(void* const* d_in, const int* in_sizes, int n_in,
                              void* d_out, int out_size, void* d_ws, size_t ws_size,
                              hipStream_t stream) {
  const float* x      = (const float*)d_in[0];
  const float* gn_w   = (const float*)d_in[1];
  const float* gn_b   = (const float*)d_in[2];
  const float* proj_w = (const float*)d_in[3];
  const float* proj_b = (const float*)d_in[4];
  const float* out_w  = (const float*)d_in[5];
  const float* out_b  = (const float*)d_in[6];
  float* out = (float*)d_out;

  char* p = (char*)d_ws;
  u16* h    = (u16*)p; p += (size_t)16 * 1024 * 512 * 2;   // h_img [64mt][16kt][8192]
  u16* q    = (u16*)p; p += (size_t)16 * 8 * 1024 * 64 * 2;
  u16* k    = (u16*)p; p += (size_t)16 * 8 * 1024 * 64 * 2;
  u16* v    = (u16*)p; p += (size_t)16 * 8 * 1024 * 64 * 2;   // [B,H,D,S]
  u16* attn = (u16*)p; p += (size_t)16 * 1024 * 512 * 2;
  u16* wq   = (u16*)p; p += (size_t)1536 * 512 * 2;           // w_img [16nt][16kt][3072]
  u16* wo   = (u16*)p; p += (size_t)512 * 512 * 2;

  gncvt_kernel<<<1536, 256, 0, stream>>>(x, gn_w, gn_b, h, proj_w, out_w, wq, wo);
  qkv_gemm<<<dim3(64, 16), 512, 0, stream>>>(h, wq, proj_b, q, k, v);
  attn_kernel<<<dim3(128, 4), 512, 0, stream>>>(q, k, v, attn);
  out_gemm<<<dim3(8, 4, 16), 256, 0, stream>>>(attn, wo, out_b, x, out);
}

// Round 12
// 197.845 us; speedup vs baseline: 1.0059x; 1.0059x over previous
//
#include <hip/hip_runtime.h>
#include <stdint.h>

typedef unsigned short u16;
typedef __attribute__((ext_vector_type(8))) short bf16x8;
typedef __attribute__((ext_vector_type(4))) short bf16x4;
typedef __attribute__((ext_vector_type(4))) float f32x4;
typedef __attribute__((ext_vector_type(4))) unsigned short u16x4;

// async global->LDS, 16B per lane, dest = wave-uniform base + lane*16
#define GLD16(gp, lp) __builtin_amdgcn_global_load_lds( \
    (__attribute__((address_space(1))) void*)(void*)(gp), \
    (__attribute__((address_space(3))) void*)(void*)(lp), 16, 0, 0)

__device__ __forceinline__ u16 f2b(float f) {  // fp32 -> bf16 bits, RNE
  union { float f; unsigned u; } v; v.f = f;
  unsigned r = v.u + 0x7FFFu + ((v.u >> 16) & 1u);
  return (u16)(r >> 16);
}

__device__ __forceinline__ float fexp2(float x) {
#if __has_builtin(__builtin_amdgcn_exp2f)
  return __builtin_amdgcn_exp2f(x);
#else
  return exp2f(x);
#endif
}

// ============================ image layouts ================================
// h_img[mt 0..63][kt 0..15][256r x 4chunks]: panel = 8192 u16 (16 KB).
//   slot(r, c8, j) = r*32 + ((c8 ^ ((r>>1)&3))*8) + j    (c8 = 8-ch chunk)
// w_img[nt 0..15][kt 0..15][96r x 4chunks]: panel = 3072 u16 (6 KB).
// attn_img[b][sm 0..7][kt 0..15][128r x 4chunks]: panel = 4096 u16 (8 KB),
//   written by attn's epilogue (same scatter cost, image addresses).
// wo_img[bn 0..3][kt 0..15][128r x 4chunks]: panel = 4096 u16 (8 KB).
// All use the same per-row swizzle; staging = flat GLD16 panel copies.
// ===========================================================================

// ---------------- fused: GroupNorm (blocks 0..511) + weight cvt (512..1535)
__global__ __launch_bounds__(256) void gncvt_kernel(const float* __restrict__ x,
                                                    const float* __restrict__ gw,
                                                    const float* __restrict__ gb,
                                                    u16* __restrict__ h,
                                                    const float* __restrict__ wq_f,
                                                    const float* __restrict__ wo_f,
                                                    u16* __restrict__ wq,
                                                    u16* __restrict__ wo) {
  if (blockIdx.x >= 512) {
    int i = (blockIdx.x - 512) * 256 + threadIdx.x;   // 0 .. 262143
    if (i < 196608) {
      // proj_w -> w_img: row n = i>>7, channels c0 = (i&127)*4
      const float4 f = ((const float4*)wq_f)[i];
      const int n = i >> 7, c0 = (i & 127) * 4;
      const int nt = n / 96, r = n - nt * 96;
      const int kt = c0 >> 5, c8 = (c0 >> 3) & 3, wi = c0 & 7;
      const int sel = (r >> 1) & 3;
      u16x4 rr; rr[0] = f2b(f.x); rr[1] = f2b(f.y); rr[2] = f2b(f.z); rr[3] = f2b(f.w);
      *(u16x4*)(wq + (size_t)(nt * 16 + kt) * 3072 + r * 32 + ((c8 ^ sel) * 8) + wi) = rr;
    } else {
      // out_w -> wo_img: row n = j>>7 (c), channels c0 = (j&127)*4
      int j = i - 196608;
      const float4 f = ((const float4*)wo_f)[j];
      const int n = j >> 7, c0 = (j & 127) * 4;
      const int bn = n >> 7, r = n & 127;
      const int kt = c0 >> 5, c8 = (c0 >> 3) & 3, wi = c0 & 7;
      const int sel = (r >> 1) & 3;
      u16x4 rr; rr[0] = f2b(f.x); rr[1] = f2b(f.y); rr[2] = f2b(f.z); rr[3] = f2b(f.w);
      *(u16x4*)(wo + (size_t)(bn * 16 + kt) * 4096 + r * 32 + ((c8 ^ sel) * 8) + wi) = rr;
    }
    return;
  }
  const int b = blockIdx.x >> 5, g = blockIdx.x & 31;
  const float* xg = x + ((size_t)(b * 512 + g * 16)) * 1024;
  const int tid = threadIdx.x;
  float4 vals[16];                 // vals[j] = channel j, pixels 4t..4t+3
  float s = 0.f, ss = 0.f;
#pragma unroll
  for (int j = 0; j < 16; j++) {
    const float4 v = ((const float4*)xg)[j * 256 + tid];
    vals[j] = v;
    s  += (v.x + v.y) + (v.z + v.w);
    ss += (v.x * v.x + v.y * v.y) + (v.z * v.z + v.w * v.w);
  }
#pragma unroll
  for (int off = 32; off; off >>= 1) { s += __shfl_down(s, off); ss += __shfl_down(ss, off); }
  __shared__ float red[8];
  const int wid = tid >> 6, lane = tid & 63;
  if (lane == 0) { red[wid] = s; red[4 + wid] = ss; }
  __syncthreads();
  if (tid == 0) {
    float S = red[0] + red[1] + red[2] + red[3];
    float SS = red[4] + red[5] + red[6] + red[7];
    float mean = S * (1.f / 16384.f);
    float var = SS * (1.f / 16384.f) - mean * mean;
    red[0] = mean; red[1] = rsqrtf(var + 1e-5f);
  }
  __syncthreads();
  const float mean = red[0], rs = red[1];
  float sc[16], bi[16];
#pragma unroll
  for (int c = 0; c < 16; c++) { sc[c] = gw[g * 16 + c] * rs; bi[c] = gb[g * 16 + c]; }
  // write into h_img: this block owns chunks {2(g&1), 2(g&1)+1} of kt = g>>1
  const int mt = b * 4 + (tid >> 6);
  const int kt = g >> 1, c8a = (g & 1) * 2;
  u16* base = h + (size_t)(mt * 16 + kt) * 8192;
#pragma unroll
  for (int e = 0; e < 4; e++) {
    const int r = (tid & 63) * 4 + e;
    const int sel = (r >> 1) & 3;
    u16 row[16];
#pragma unroll
    for (int j = 0; j < 16; j++) {
      const float v = (e == 0) ? vals[j].x : (e == 1) ? vals[j].y : (e == 2) ? vals[j].z : vals[j].w;
      row[j] = f2b((v - mean) * sc[j] + bi[j]);
    }
    *(bf16x8*)(base + r * 32 + ((c8a ^ sel) * 8)) = *(bf16x8*)&row[0];
    *(bf16x8*)(base + r * 32 + (((c8a + 1) ^ sel) * 8)) = *(bf16x8*)&row[8];
  }
}

// ---------------- QKV GEMM v7: 2-deep pipeline (counted vmcnt) ------------
__global__ __launch_bounds__(512, 4) void qkv_gemm(const u16* __restrict__ h,
                                                   const u16* __restrict__ w,
                                                   const float* __restrict__ bias,
                                                   u16* __restrict__ q,
                                                   u16* __restrict__ k,
                                                   u16* __restrict__ v) {
  __shared__ u16 Hs[3][8192];   // 3 x 16 KB
  __shared__ u16 Ws[3][3072];   // 3 x 6 KB
  const int bm = blockIdx.x;    // 0..63  (256 s)
  const int bn = blockIdx.y;    // 0..15  (96 channels)
  const int tid = threadIdx.x, lane = tid & 63, wid = tid >> 6;
  const int wm = wid >> 1, wn = wid & 1;     // wm: 4 s-col waves, wn: 2 ch-row waves
  const int c15 = lane & 15, quad = lane >> 4;
  const int kc = ((quad ^ ((c15 >> 1) & 3)) * 8);   // phys chunk offset (u16)

  const u16* pA = h + (size_t)bm * 16 * 8192 + (size_t)tid * 8;   // + kt*8192
  const u16* pB = w + (size_t)bn * 16 * 3072 + (size_t)tid * 8;   // + kt*3072
  const bool doB = (tid < 384);

  const f32x4 fz = {0.f, 0.f, 0.f, 0.f};
  f32x4 acc[3][4];              // [ch-tile ci][s-tile si]
#pragma unroll
  for (int i = 0; i < 3; i++)
#pragma unroll
    for (int j = 0; j < 4; j++) acc[i][j] = fz;

#define STAGE(T, B) { const u16* a_ = pA + (size_t)(T) * 8192; \
    GLD16(a_, &Hs[B][tid * 8]); \
    GLD16(a_ + 4096, &Hs[B][4096 + tid * 8]); \
    if (doB) GLD16(pB + (size_t)(T) * 3072, &Ws[B][tid * 8]); }

  // prologue: tiles 0,1 in flight
  STAGE(0, 0)
  STAGE(1, 1)

#pragma unroll
  for (int kt = 0; kt < 16; ++kt) {
    const int cb = kt % 3;
    __builtin_amdgcn_s_barrier();      // readers of buf (kt+2)%3 (tile kt-1) done
    if (kt < 14) STAGE(kt + 2, (kt + 2) % 3)
    // counted wait: tile kt's loads are the oldest; leave tiles kt+1,kt+2 in flight
    if (kt < 14) {
      if (doB) asm volatile("s_waitcnt vmcnt(6)" ::: "memory");
      else     asm volatile("s_waitcnt vmcnt(4)" ::: "memory");
    } else if (kt == 14) {
      if (doB) asm volatile("s_waitcnt vmcnt(3)" ::: "memory");
      else     asm volatile("s_waitcnt vmcnt(2)" ::: "memory");
    } else {
      asm volatile("s_waitcnt vmcnt(0)" ::: "memory");
    }
    __builtin_amdgcn_s_barrier();      // publish tile kt (all waves' loads done)
    __builtin_amdgcn_sched_barrier(0);
    bf16x8 af[3], bf[4];
#pragma unroll
    for (int ci = 0; ci < 3; ci++)
      af[ci] = *(const bf16x8*)&Ws[cb][(wn * 48 + ci * 16 + c15) * 32 + kc];
#pragma unroll
    for (int si = 0; si < 4; si++)
      bf[si] = *(const bf16x8*)&Hs[cb][(wm * 64 + si * 16 + c15) * 32 + kc];
    __builtin_amdgcn_s_setprio(1);
#pragma unroll
    for (int ci = 0; ci < 3; ci++)
#pragma unroll
      for (int si = 0; si < 4; si++)
        acc[ci][si] = __builtin_amdgcn_mfma_f32_16x16x32_bf16(af[ci], bf[si], acc[ci][si], 0, 0, 0);
    __builtin_amdgcn_s_setprio(0);
  }
#undef STAGE

  const float qscale = 0.51006972f;            // 2^-1.5 * log2(e)
  const float kscale = 0.35355339059327373f;   // 2^-1.5
  const int b = bm >> 2;
#pragma unroll
  for (int ci = 0; ci < 3; ci++) {
    const int n0 = bn * 96 + wn * 48 + ci * 16 + quad * 4;   // rows n0..n0+3
    const int head = n0 / 192;
    const int rr = n0 - head * 192;
    const int d0 = rr & 63;
    const float4 bi4 = *(const float4*)&bias[n0];
    const float bb[4] = {bi4.x, bi4.y, bi4.z, bi4.w};
#pragma unroll
    for (int si = 0; si < 4; si++) {
      const int sp = (bm & 3) * 256 + wm * 64 + si * 16 + c15;
      if (rr < 128) {
        u16* dst = ((rr < 64) ? q : k) + ((size_t)(b * 8 + head) * 1024 + sp) * 64 + d0;
        const float sc = (rr < 64) ? qscale : kscale;
        u16x4 pk;
#pragma unroll
        for (int r = 0; r < 4; r++) pk[r] = f2b((acc[ci][si][r] + bb[r]) * sc);
        *(u16x4*)dst = pk;
      } else {
#pragma unroll
        for (int r = 0; r < 4; r++)
          v[((size_t)(b * 8 + head) * 64 + d0 + r) * 1024 + sp] = f2b(acc[ci][si][r] + bb[r]);
      }
    }
  }
}

// ---------------- flash attention v11 (r10 revert) + image-layout epilogue -
__global__ __launch_bounds__(512) void attn_kernel(const u16* __restrict__ q,
                                                   const u16* __restrict__ k,
                                                   const u16* __restrict__ vT,
                                                   u16* __restrict__ o) {
  __shared__ u16 Ks[2][64 * 64];
  __shared__ u16 Vs[2][64 * 64];
  const int bh = blockIdx.x;
  const int qb = blockIdx.y;      // 0..3
  const int tid = threadIdx.x, lane = tid & 63, wid = tid >> 6;   // wid 0..7
  const u16* Q = q + (size_t)bh * 1024 * 64;
  const u16* K = k + (size_t)bh * 1024 * 64;
  const u16* V = vT + (size_t)bh * 64 * 1024;
  const int qrow0 = qb * 256 + wid * 32;
  const int c15 = lane & 15, quad = lane >> 4;
  const int sw = c15 & 7;                  // read-side swizzle component
  const int srow = tid >> 3;               // 0..63
  const int u8g  = tid & 7;                // 8-col group (K) / 8-key group (V)
  const int s7 = srow & 7;
  const int kld = srow * 64 + ((u8g ^ s7) * 8);
  const int ve = 4 * (u8g >> 2) + 2 * (u8g & 1);   // pc0>>1
  const int vc = ((u8g >> 1) & 1) * 4;             // (pc0&1)*4
  const int vld0 = srow * 64 + ((ve ^ s7) * 8) + vc;
  const int vld1 = srow * 64 + (((ve + 1) ^ s7) * 8) + vc;

  bf16x8 qf[2][2];
#pragma unroll
  for (int kk = 0; kk < 2; kk++)
#pragma unroll
    for (int ni = 0; ni < 2; ni++)
      qf[kk][ni] = *(const bf16x8*)(Q + (size_t)(qrow0 + ni * 16 + c15) * 64 + kk * 32 + quad * 8);

  const f32x4 fz = {0.f, 0.f, 0.f, 0.f};
  const float Mshift = 14.4269504089f;     // 10 * log2(e)
  const f32x4 fmseed = {-Mshift, -Mshift, -Mshift, -Mshift};
  bf16x8 vone;
#pragma unroll
  for (int i = 0; i < 8; i++) vone[i] = (short)0x3F80;   // bf16 1.0
  f32x4 oaccT[4][2];               // O^T[d-tile nd][qrow-tile ni]
#pragma unroll
  for (int i = 0; i < 4; i++)
#pragma unroll
    for (int j = 0; j < 2; j++) oaccT[i][j] = fz;
  f32x4 accl[2] = {fz, fz};        // denominator via ones-MFMA

  bf16x8 kr, vr;
  kr = *(const bf16x8*)(K + (size_t)srow * 64 + u8g * 8);
  vr = *(const bf16x8*)(V + (size_t)srow * 1024 + u8g * 8);
  {
    u16* Kd = Ks[0]; u16* Vd = Vs[0];
    *(bf16x8*)&Kd[kld] = kr;
    union { bf16x4 h[2]; bf16x8 v; } a; a.v = vr;
    *(bf16x4*)&Vd[vld0] = a.h[0];
    *(bf16x4*)&Vd[vld1] = a.h[1];
  }
  kr = *(const bf16x8*)(K + (size_t)(64 + srow) * 64 + u8g * 8);
  vr = *(const bf16x8*)(V + (size_t)srow * 1024 + 64 + u8g * 8);

  for (int kt = 0; kt < 16; ++kt) {
    __syncthreads();   // publish buf[kt&1]; retire readers of buf[(kt&1)^1]
    const int cur = kt & 1, alt = cur ^ 1;
    if (kt < 15) {
      u16* Kd = Ks[alt]; u16* Vd = Vs[alt];
      *(bf16x8*)&Kd[kld] = kr;
      union { bf16x4 h[2]; bf16x8 v; } a; a.v = vr;
      *(bf16x4*)&Vd[vld0] = a.h[0];
      *(bf16x4*)&Vd[vld1] = a.h[1];
      const int pk2 = (kt + 2) & 15;
      kr = *(const bf16x8*)(K + ((size_t)pk2 * 64 + srow) * 64 + u8g * 8);
      vr = *(const bf16x8*)(V + (size_t)srow * 1024 + pk2 * 64 + u8g * 8);
    }
    const u16* Kc = Ks[cur];
    const u16* Vc = Vs[cur];

    // S^T = K Q^T; kk=0 seeds D with fmseed via the C operand (no v_movs)
    f32x4 sacc[4][2];
    {
      bf16x8 af[4];
#pragma unroll
      for (int mi = 0; mi < 4; mi++)
        af[mi] = *(const bf16x8*)&Kc[(mi * 16 + c15) * 64 + (((quad) ^ sw) * 8)];
      __builtin_amdgcn_s_setprio(1);
#pragma unroll
      for (int mi = 0; mi < 4; mi++)
#pragma unroll
        for (int ni = 0; ni < 2; ni++)
          sacc[mi][ni] = __builtin_amdgcn_mfma_f32_16x16x32_bf16(af[mi], qf[0][ni], fmseed, 0, 0, 0);
      __builtin_amdgcn_s_setprio(0);
    }
    {
      bf16x8 af[4];
#pragma unroll
      for (int mi = 0; mi < 4; mi++)
        af[mi] = *(const bf16x8*)&Kc[(mi * 16 + c15) * 64 + (((4 + quad) ^ sw) * 8)];
      __builtin_amdgcn_s_setprio(1);
#pragma unroll
      for (int mi = 0; mi < 4; mi++)
#pragma unroll
        for (int ni = 0; ni < 2; ni++)
          sacc[mi][ni] = __builtin_amdgcn_mfma_f32_16x16x32_bf16(af[mi], qf[1][ni], sacc[mi][ni], 0, 0, 0);
      __builtin_amdgcn_s_setprio(0);
    }

    // P = exp2(s') packed to bf16 pairs IN REGISTERS (truncation)
    unsigned pkd[4][2][2];   // [key-tile mi][ni][dword]
#pragma unroll
    for (int ni = 0; ni < 2; ni++) {
#pragma unroll
      for (int mi = 0; mi < 4; mi++) {
        unsigned pu[4];
#pragma unroll
        for (int r = 0; r < 4; r++) {
          const float p = fexp2(sacc[mi][ni][r]);
          union { float f; unsigned u; } c; c.f = p;
          pu[r] = c.u;
        }
        pkd[mi][ni][0] = __builtin_amdgcn_perm(pu[1], pu[0], 0x07060302u);
        pkd[mi][ni][1] = __builtin_amdgcn_perm(pu[3], pu[2], 0x07060302u);
      }
    }

    // O^T += V^T P^T ; l += ones^T P^T (denominator on the MFMA pipe)
#pragma unroll
    for (int mg = 0; mg < 2; mg++) {
      union { unsigned u[4]; bf16x8 v; } bb[2];
#pragma unroll
      for (int ni = 0; ni < 2; ni++) {
        bb[ni].u[0] = pkd[2 * mg][ni][0];     bb[ni].u[1] = pkd[2 * mg][ni][1];
        bb[ni].u[2] = pkd[2 * mg + 1][ni][0]; bb[ni].u[3] = pkd[2 * mg + 1][ni][1];
      }
      bf16x8 aa[4];
#pragma unroll
      for (int nd = 0; nd < 4; nd++)
        aa[nd] = *(const bf16x8*)&Vc[(nd * 16 + c15) * 64 + (((mg * 4 + quad) ^ sw) * 8)];
      __builtin_amdgcn_s_setprio(1);
#pragma unroll
      for (int nd = 0; nd < 4; nd++)
#pragma unroll
        for (int ni = 0; ni < 2; ni++)
          oaccT[nd][ni] = __builtin_amdgcn_mfma_f32_16x16x32_bf16(aa[nd], bb[ni].v, oaccT[nd][ni], 0, 0, 0);
#pragma unroll
      for (int ni = 0; ni < 2; ni++)
        accl[ni] = __builtin_amdgcn_mfma_f32_16x16x32_bf16(vone, bb[ni].v, accl[ni], 0, 0, 0);
      __builtin_amdgcn_s_setprio(0);
    }
  }

  // denominator already per-qrow in accl (all rows/regs equal) — no shfl
  float iv[2];
#pragma unroll
  for (int ni = 0; ni < 2; ni++) iv[ni] = 1.f / accl[ni][0];
  const int b = bh >> 3, hh = bh & 7;
#pragma unroll
  for (int ni = 0; ni < 2; ni++) {
    const int row = qrow0 + ni * 16 + c15;
    const int sm = row >> 7, r = row & 127;
    const int sel = (r >> 1) & 3;
#pragma unroll
    for (int nd = 0; nd < 4; nd++) {
      u16x4 pk4;
#pragma unroll
      for (int rr = 0; rr < 4; rr++) pk4[rr] = f2b(oaccT[nd][ni][rr] * iv[ni]);
      const int ch = hh * 64 + nd * 16 + quad * 4;
      const int kt = ch >> 5, c8 = (ch >> 3) & 3, j = ch & 7;
      *(u16x4*)(o + ((size_t)((b * 8 + sm) * 16 + kt)) * 4096
                  + r * 32 + ((c8 ^ sel) * 8) + j) = pk4;
    }
  }
}

// ---------------- out proj v3: image staging + swizzled reads -------------
// Same 2-deep counted-vmcnt pipeline as r10; staging is now flat GLD16 panel
// copies from attn_img / wo_img (was 64B-segment scatter) and the LDS reads
// use the image swizzle (was an 8-way-conflict 64B-stride layout).
__global__ __launch_bounds__(256) void out_gemm(const u16* __restrict__ attnimg,
                                                const u16* __restrict__ woimg,
                                                const float* __restrict__ ob,
                                                const float* __restrict__ x,
                                                float* __restrict__ out) {
  __shared__ u16 As[3][4096];   // 3 x 8 KB
  __shared__ u16 Bs[3][4096];   // 3 x 8 KB
  const int b = blockIdx.z;
  const int bm = blockIdx.x;      // s-tile 0..7
  const int bn = blockIdx.y;      // c-tile 0..3
  const int tid = threadIdx.x, lane = tid & 63, wid = tid >> 6;
  const int wm = wid & 1, wn = wid >> 1;
  const int c15 = lane & 15, quad = lane >> 4;
  const int kc = ((quad ^ ((c15 >> 1) & 3)) * 8);

  const u16* pA = attnimg + (size_t)((b * 8 + bm) * 16) * 4096 + (size_t)tid * 8; // + kt*4096
  const u16* pB = woimg + (size_t)(bn * 16) * 4096 + (size_t)tid * 8;             // + kt*4096

  const f32x4 fz = {0.f, 0.f, 0.f, 0.f};
  f32x4 acc[4][4];
#pragma unroll
  for (int i = 0; i < 4; i++)
#pragma unroll
    for (int j = 0; j < 4; j++) acc[i][j] = fz;

#define OSTAGE(T, B) { \
    GLD16(pA + (size_t)(T) * 4096,        &As[B][tid * 8]); \
    GLD16(pA + (size_t)(T) * 4096 + 2048, &As[B][2048 + tid * 8]); \
    GLD16(pB + (size_t)(T) * 4096,        &Bs[B][tid * 8]); \
    GLD16(pB + (size_t)(T) * 4096 + 2048, &Bs[B][2048 + tid * 8]); }

  // prologue: tiles 0,1 in flight (8 loads/thread)
  OSTAGE(0, 0)
  OSTAGE(1, 1)

#pragma unroll
  for (int kt = 0; kt < 16; ++kt) {
    const int cb = kt % 3;
    __builtin_amdgcn_s_barrier();      // readers of buf (kt+2)%3 (tile kt-1) done
    if (kt < 14) OSTAGE(kt + 2, (kt + 2) % 3)
    // counted wait: tile kt's 4 loads are the oldest outstanding
    if (kt < 14)       asm volatile("s_waitcnt vmcnt(8)" ::: "memory");
    else if (kt == 14) asm volatile("s_waitcnt vmcnt(4)" ::: "memory");
    else               asm volatile("s_waitcnt vmcnt(0)" ::: "memory");
    __builtin_amdgcn_s_barrier();      // publish tile kt
    __builtin_amdgcn_sched_barrier(0);
    bf16x8 af[4], bf[4];
#pragma unroll
    for (int mi = 0; mi < 4; mi++)
      af[mi] = *(const bf16x8*)&As[cb][(wm * 64 + mi * 16 + c15) * 32 + kc];
#pragma unroll
    for (int ni = 0; ni < 4; ni++)
      bf[ni] = *(const bf16x8*)&Bs[cb][(wn * 64 + ni * 16 + c15) * 32 + kc];
    __builtin_amdgcn_s_setprio(1);
#pragma unroll
    for (int mi = 0; mi < 4; mi++)
#pragma unroll
      for (int ni = 0; ni < 4; ni++)
        acc[mi][ni] = __builtin_amdgcn_mfma_f32_16x16x32_bf16(af[mi], bf[ni], acc[mi][ni], 0, 0, 0);
    __builtin_amdgcn_s_setprio(0);
  }
#undef OSTAGE

  const int quad4 = quad << 2;
#pragma unroll
  for (int mi = 0; mi < 4; mi++) {
    const int m = bm * 128 + wm * 64 + mi * 16 + quad4;   // s base (rows m..m+3)
#pragma unroll
    for (int ni = 0; ni < 4; ni++) {
      const int c = bn * 128 + wn * 64 + ni * 16 + c15;
      const float bo = ob[c];
      const size_t idx = ((size_t)b * 512 + c) * 1024 + m;
      const float4 xv = *(const float4*)(x + idx);
      float4 ov;
      ov.x = acc[mi][ni][0] + bo + xv.x;
      ov.y = acc[mi][ni][1] + bo + xv.y;
      ov.z = acc[mi][ni][2] + bo + xv.z;
      ov.w = acc[mi][ni][3] + bo + xv.w;
      *(float4*)(out + idx) = ov;
    }
  }
}

extern "C" void kernel_launch(void* const* d_in, const int* in_sizes, int n_in,
                              void* d_out, int out_size, void* d_ws, size_t ws_size,
                              hipStream_t stream) {
  const float* x      = (const float*)d_in[0];
  const float* gn_w   = (const float*)d_in[1];
  const float* gn_b   = (const float*)d_in[2];
  const float* proj_w = (const float*)d_in[3];
  const float* proj_b = (const float*)d_in[4];
  const float* out_w  = (const float*)d_in[5];
  const float* out_b  = (const float*)d_in[6];
  float* out = (float*)d_out;

  char* p = (char*)d_ws;
  u16* h    = (u16*)p; p += (size_t)16 * 1024 * 512 * 2;   // h_img [64mt][16kt][8192]
  u16* q    = (u16*)p; p += (size_t)16 * 8 * 1024 * 64 * 2;
  u16* k    = (u16*)p; p += (size_t)16 * 8 * 1024 * 64 * 2;
  u16* v    = (u16*)p; p += (size_t)16 * 8 * 1024 * 64 * 2;   // [B,H,D,S]
  u16* attn = (u16*)p; p += (size_t)16 * 1024 * 512 * 2;      // attn_img [B][8sm][16kt][4096]
  u16* wq   = (u16*)p; p += (size_t)1536 * 512 * 2;           // w_img [16nt][16kt][3072]
  u16* wo   = (u16*)p; p += (size_t)512 * 512 * 2;            // wo_img [4bn][16kt][4096]

  gncvt_kernel<<<1536, 256, 0, stream>>>(x, gn_w, gn_b, h, proj_w, out_w, wq, wo);
  qkv_gemm<<<dim3(64, 16), 512, 0, stream>>>(h, wq, proj_b, q, k, v);
  attn_kernel<<<dim3(128, 4), 512, 0, stream>>>(q, k, v, attn);
  out_gemm<<<dim3(8, 4, 16), 256, 0, stream>>>(attn, wo, out_b, x, out);
}